// Round 1
// 245.734 us; speedup vs baseline: 1.0179x; 1.0179x over previous
//
#include <hip/hip_runtime.h>

#define B_    64
#define C_    2048
#define HW_   288
#define EPS_  0.07f
#define TINY_ 1e-8f
#define NCH_  64
#define CPC_  (C_ / NCH_)   // 32 rows per chunk
#define NGRP_ 16            // chunk-groups per batch (4 chunks / group = 1 block)

__device__ __forceinline__ float comp(const float4 v, int i) {
  return i == 0 ? v.x : i == 1 ? v.y : i == 2 ? v.z : v.w;
}

__device__ __forceinline__ void acc3(const float4 v, float a0, float a1,
                                     float* ssq, float* sd0, float* sd1) {
  ssq[0] += v.x * v.x; ssq[1] += v.y * v.y; ssq[2] += v.z * v.z; ssq[3] += v.w * v.w;
  sd0[0] += v.x * a0;  sd0[1] += v.y * a0;  sd0[2] += v.z * a0;  sd0[3] += v.w * a0;
  sd1[0] += v.x * a1;  sd1[1] += v.y * a1;  sd1[2] += v.z * a1;  sd1[3] += v.w * a1;
}

// ---------------------------------------------------------------------------
// Kernel 1: per-token partial sums, one C-chunk per WAVE, x-rows AND anchors
// double-buffered in 4-row groups. NEW: the 4 waves of a block combine their
// chunk partials in LDS before writing, shrinking `part` 4x (14.2 -> 3.5 MB).
// grid = B*NCH/4 = 1024 blocks, 256 threads.
// part layout: [B][NGRP_][3 planes][288] (3.54 MB).
// ---------------------------------------------------------------------------
__global__ __launch_bounds__(256) void k1_partials(
    const float* __restrict__ x, const float* __restrict__ anchors,
    float* __restrict__ part) {
  __shared__ float4 lds[4][3][72];   // [wave][plane][float4 token-quad] = 13.8 KB

  int bi = blockIdx.x;
  int b  = bi >> 4;                // NGRP_ = 16 chunk-groups per b
  int cg = bi & 15;
  int t = threadIdx.x, lane = t & 63, wid = t >> 6;
  int ch = cg * 4 + wid;
  int c0 = ch * CPC_;
  const float* xb = x + ((size_t)b * C_ + c0) * HW_;
  const float4* a0v = (const float4*)(anchors + c0);        // c0 % 32 == 0
  const float4* a1v = (const float4*)(anchors + C_ + c0);

  float ssq[4] = {0,0,0,0}, sd0[4] = {0,0,0,0}, sd1[4] = {0,0,0,0};

  float4 xbuf[4], abuf0, abuf1;
#pragma unroll
  for (int j = 0; j < 4; ++j)
    xbuf[j] = ((const float4*)(xb + (size_t)j * HW_))[lane];
  abuf0 = a0v[0];
  abuf1 = a1v[0];

#pragma unroll 1
  for (int r = 0; r < CPC_; r += 4) {
    float4 xcur[4], ac0 = abuf0, ac1 = abuf1;
#pragma unroll
    for (int j = 0; j < 4; ++j) xcur[j] = xbuf[j];
    if (r + 4 < CPC_) {
#pragma unroll
      for (int j = 0; j < 4; ++j)
        xbuf[j] = ((const float4*)(xb + (size_t)(r + 4 + j) * HW_))[lane];
      abuf0 = a0v[(r >> 2) + 1];
      abuf1 = a1v[(r >> 2) + 1];
    }
#pragma unroll
    for (int j = 0; j < 4; ++j)
      acc3(xcur[j], comp(ac0, j), comp(ac1, j), ssq, sd0, sd1);
  }

  // tail: h float4s 64..71 (one 128B line per row); rows k*8+(lane>>3)
  int rg = lane >> 3, q = lane & 7;
  float4 tv[4];
  float ta0[4], ta1[4];
#pragma unroll
  for (int k = 0; k < CPC_ / 8; ++k) {
    int r = k * 8 + rg;
    tv[k]  = ((const float4*)(xb + (size_t)r * HW_))[64 + q];
    ta0[k] = anchors[c0 + r];
    ta1[k] = anchors[C_ + c0 + r];
  }
  float tsq[4] = {0,0,0,0}, td0[4] = {0,0,0,0}, td1[4] = {0,0,0,0};
#pragma unroll
  for (int k = 0; k < CPC_ / 8; ++k)
    acc3(tv[k], ta0[k], ta1[k], tsq, td0, td1);
#pragma unroll
  for (int off = 8; off < 64; off <<= 1) {
#pragma unroll
    for (int j = 0; j < 4; ++j) {
      tsq[j] += __shfl_xor(tsq[j], off);
      td0[j] += __shfl_xor(td0[j], off);
      td1[j] += __shfl_xor(td1[j], off);
    }
  }

  // Stage this wave's 3x288-float chunk partials into LDS.
  lds[wid][0][lane] = make_float4(ssq[0], ssq[1], ssq[2], ssq[3]);
  lds[wid][1][lane] = make_float4(sd0[0], sd0[1], sd0[2], sd0[3]);
  lds[wid][2][lane] = make_float4(sd1[0], sd1[1], sd1[2], sd1[3]);
  if (lane < 8) {
    lds[wid][0][64 + lane] = make_float4(tsq[0], tsq[1], tsq[2], tsq[3]);
    lds[wid][1][64 + lane] = make_float4(td0[0], td0[1], td0[2], td0[3]);
    lds[wid][2][64 + lane] = make_float4(td1[0], td1[1], td1[2], td1[3]);
  }
  __syncthreads();

  // Combine the 4 waves' chunks and write ONE group-partial (3*288 floats).
  // 216 float4 sums; threads 0..215, coalesced 16B writes.
  if (t < 216) {
    int p = t / 72, i = t - p * 72;
    float4 s0 = lds[0][p][i], s1 = lds[1][p][i];
    float4 s2 = lds[2][p][i], s3 = lds[3][p][i];
    float4 s = make_float4(s0.x + s1.x + s2.x + s3.x,
                           s0.y + s1.y + s2.y + s3.y,
                           s0.z + s1.z + s2.z + s3.z,
                           s0.w + s1.w + s2.w + s3.w);
    ((float4*)(part + ((size_t)(b * NGRP_ + cg) * 3 + p) * HW_))[i] = s;
  }
}

// Block-wide 2-value sum reduction for 320 threads (5 full waves).
__device__ __forceinline__ void block_reduce2(
    float& p0, float& p1, volatile float* red0, volatile float* red1,
    int t, int nw) {
  int lane = t & 63, wid = t >> 6;
#pragma unroll
  for (int off = 32; off >= 1; off >>= 1) {
    p0 += __shfl_down(p0, off);
    p1 += __shfl_down(p1, off);
  }
  __syncthreads();
  if (lane == 0) { red0[wid] = p0; red1[wid] = p1; }
  __syncthreads();
  float s0 = 0.f, s1 = 0.f;
  for (int w = 0; w < nw; ++w) { s0 += red0[w]; s1 += red1[w]; }
  p0 = s0; p1 = s1;
}

// ---------------------------------------------------------------------------
// Kernel 2: group-collapse + per-batch Sinkhorn fused. grid = 64 blocks,
// 320 threads. Token t sums its 3 stats over NGRP_=16 group-partials (48
// fully-unrolled coalesced loads; was 192 at unroll 8), then runs the 7
// Sinkhorn iterations. m -> out_m, 1/den -> invden.
// ---------------------------------------------------------------------------
__global__ __launch_bounds__(320) void k2_sinkhorn(
    const float* __restrict__ part, const float* __restrict__ anchors,
    float* __restrict__ out_m, float* __restrict__ invden) {
  int b = blockIdx.x, t = threadIdx.x;
  __shared__ float red0[8], red1[8];
  const int nw = 5;

  float a0 = 0.f, a1 = 0.f;
  for (int c = t; c < C_; c += 320) {
    float q0 = anchors[c], q1 = anchors[C_ + c];
    a0 += q0 * q0; a1 += q1 * q1;
  }
  block_reduce2(a0, a1, red0, red1, t, nw);
  float ian0 = 1.0f / fmaxf(sqrtf(a0), 1e-12f);
  float ian1 = 1.0f / fmaxf(sqrtf(a1), 1e-12f);

  float K0 = 0.f, K1 = 0.f;
  if (t < HW_) {
    const float* p = part + (size_t)b * NGRP_ * 3 * HW_ + t;
    float ssq = 0.f, d0 = 0.f, d1 = 0.f;
#pragma unroll
    for (int g = 0; g < NGRP_; ++g) {
      const float* q = p + (size_t)g * 3 * HW_;
      ssq += q[0];
      d0  += q[HW_];
      d1  += q[2 * HW_];
    }
    float ixn = 1.0f / fmaxf(sqrtf(ssq), 1e-12f);
    K0 = expf((d0 * ixn * ian0 - 1.0f) / EPS_) + TINY_;
    K1 = expf((d1 * ixn * ian1 - 1.0f) / EPS_) + TINY_;
  }

  float v0 = 1.f, v1 = 1.f, u = 0.f;
  for (int it = 0; it < 7; ++it) {
    if (t < HW_) u = (1.0f / (float)HW_) / (K0 * v0 + K1 * v1 + TINY_);
    float p0 = K0 * u, p1 = K1 * u;
    block_reduce2(p0, p1, red0, red1, t, nw);
    v0 = 0.5f / (p0 + TINY_);
    v1 = 0.5f / (p1 + TINY_);
  }

  float m0 = 0.f, m1 = 0.f;
  if (t < HW_) {
    m0 = K0 * u * v0 * (float)HW_;
    m1 = K1 * u * v1 * (float)HW_;
  }
  float q0 = m0, q1 = m1;
  block_reduce2(q0, q1, red0, red1, t, nw);
  if (t < HW_) {
    out_m[(b * 2 + 0) * HW_ + t] = m0;
    out_m[(b * 2 + 1) * HW_ + t] = m1;
  }
  if (t == 0) {
    invden[b * 2 + 0] = 1.0f / (q0 + 1e-6f);
    invden[b * 2 + 1] = 1.0f / (q1 + 1e-6f);
  }
}

// ---------------------------------------------------------------------------
// Kernel 3: masked pooling. TRANSACTION-COALESCED octant mapping: for load
// index j, octant `oct` reads float4 (oct + 8*j) — the 8 octs of a row cover
// ONE contiguous 128B line per instruction. Mask fragments w[j]=m[oct+8j]
// stay register-resident across all 128 rows. Row combine: 3 shfl_xor pairs.
// grid = B*16 = 1024 blocks, 256 threads, 4 row-groups each.
// ---------------------------------------------------------------------------
__global__ __launch_bounds__(256) void k3_pool(
    const float* __restrict__ x, const float* __restrict__ m,
    const float* __restrict__ invden, float* __restrict__ out) {
  int bi = blockIdx.x;
  int b = bi >> 4, seg = bi & 15;
  int t = threadIdx.x, oct = t & 7, rl = t >> 3;   // rl = 0..31

  const float4* m0 = (const float4*)(m + (b * 2 + 0) * HW_);
  const float4* m1 = (const float4*)(m + (b * 2 + 1) * HW_);
  float4 w0[9], w1[9];
#pragma unroll
  for (int j = 0; j < 9; ++j) {
    w0[j] = m0[oct + 8 * j];
    w1[j] = m1[oct + 8 * j];
  }
  float inv0 = invden[2 * b], inv1 = invden[2 * b + 1];

  int cbase = seg * 128;
#pragma unroll 1
  for (int g = 0; g < 4; ++g) {
    int c = cbase + g * 32 + rl;
    const float4* xr = (const float4*)(x + ((size_t)b * C_ + c) * HW_);
    float4 xa[9];
#pragma unroll
    for (int j = 0; j < 9; ++j) xa[j] = xr[oct + 8 * j];
    float a0 = 0.f, a1 = 0.f;
#pragma unroll
    for (int j = 0; j < 9; ++j) {
      a0 += xa[j].x * w0[j].x + xa[j].y * w0[j].y + xa[j].z * w0[j].z + xa[j].w * w0[j].w;
      a1 += xa[j].x * w1[j].x + xa[j].y * w1[j].y + xa[j].z * w1[j].z + xa[j].w * w1[j].w;
    }
#pragma unroll
    for (int off = 4; off >= 1; off >>= 1) {
      a0 += __shfl_xor(a0, off);
      a1 += __shfl_xor(a1, off);
    }
    if (oct == 0) {
      out[(size_t)b * C_ + c] = a0 * inv0;
      out[(size_t)B_ * C_ + (size_t)b * C_ + c] = a1 * inv1;
    }
  }
}

extern "C" void kernel_launch(void* const* d_in, const int* in_sizes, int n_in,
                              void* d_out, int out_size, void* d_ws, size_t ws_size,
                              hipStream_t stream) {
  const float* x       = (const float*)d_in[0];
  const float* anchors = (const float*)d_in[1];
  float* out = (float*)d_out;

  // ws layout: invden[128] | part[B*NGRP_*3*288]  (~3.54 MB)
  float* invden = (float*)d_ws;
  float* part = invden + 128;

  float* out_m = out + 2 * B_ * C_;  // m region of d_out (B,2,H,W)

  k1_partials<<<B_ * (NCH_ / 4), 256, 0, stream>>>(x, anchors, part);
  k2_sinkhorn<<<B_, 320, 0, stream>>>(part, anchors, out_m, invden);
  k3_pool<<<B_ * 16, 256, 0, stream>>>(x, out_m, invden, out);
}